// Round 5
// baseline (231.437 us; speedup 1.0000x reference)
//
#include <hip/hip_runtime.h>
#include <hip/hip_bf16.h>

#define TOK 16384
#define HD  1024
#define DD  256
#define NE  8

typedef __attribute__((ext_vector_type(8))) short short8;
typedef __attribute__((ext_vector_type(4))) float floatx4;
typedef unsigned short u16;

static __device__ __forceinline__ u16 f2bf(float f) {
  __hip_bfloat16 h = __float2bfloat16(f);
  return *reinterpret_cast<u16*>(&h);
}
// convert 8 consecutive fp32 (16B-aligned) -> bf16 short8
static __device__ __forceinline__ short8 cvt8(const float* p) {
  float4 a = *(const float4*)p;
  float4 b = *(const float4*)(p + 4);
  u16 t[8] = {f2bf(a.x), f2bf(a.y), f2bf(a.z), f2bf(a.w),
              f2bf(b.x), f2bf(b.y), f2bf(b.z), f2bf(b.w)};
  return *(short8*)t;
}

// async direct global->LDS: wave writes lds_base + lane*16 (1KB/instr),
// per-lane global source (pre-swizzled upstream).
static __device__ __forceinline__ void gl16(const u16* g, u16* l) {
  __builtin_amdgcn_global_load_lds(
      (const __attribute__((address_space(1))) void*)g,
      (__attribute__((address_space(3))) void*)l, 16, 0, 0);
}

// ---- prep: weight transpose->bf16 (blocks 0..1535) + router (blocks 1536..3583)
// router: 8 tokens/block, 2 serial tokens per wave (short chain, many blocks);
// emits bf16 copy of x (xbf) for gemm1's A operand.
__global__ __launch_bounds__(256) void prep_kernel(
    const float* __restrict__ wg, const float* __restrict__ wu,
    const float* __restrict__ wd, const float* __restrict__ x,
    const float* __restrict__ gw,
    u16* __restrict__ wgT, u16* __restrict__ wuT, u16* __restrict__ wdT,
    u16* __restrict__ xbf,
    int* __restrict__ counts, int* __restrict__ tlist)
{
  __shared__ u16 tile[64][72];
  __shared__ int sexp[8];
  __shared__ int sbase[NE];
  int bid = blockIdx.x;
  int tid = threadIdx.x;

  if (bid < 1536) {
    const float* src; u16* dst; int R, C;
    if (bid < 512)       { src = wg; dst = wgT; R = HD; C = DD; }
    else if (bid < 1024) { src = wu; dst = wuT; R = HD; C = DD; bid -= 512; }
    else                 { src = wd; dst = wdT; R = DD; C = HD; bid -= 1024; }
    int e = bid >> 6, t = bid & 63;
    int ntc = C >> 6;
    int tr = t / ntc, tc = t % ntc;
    int r = tid >> 2, c0 = (tid & 3) * 16;
    const float* s = src + (size_t)e * R * C + (size_t)(tr * 64 + r) * C + tc * 64 + c0;
    *(short8*)&tile[r][c0]     = cvt8(s);
    *(short8*)&tile[r][c0 + 8] = cvt8(s + 8);
    __syncthreads();
    int c = tid >> 2, r0 = (tid & 3) * 16;
    alignas(16) u16 buf[16];
    for (int j = 0; j < 16; ++j) buf[j] = tile[r0 + j][c];
    u16* d = dst + (size_t)e * R * C + (size_t)(tc * 64 + c) * R + tr * 64 + r0;
    *(float4*)(d)     = *(const float4*)&buf[0];
    *(float4*)(d + 8) = *(const float4*)&buf[8];
    return;
  }

  // ---- router: 8 tokens/block, fp32-exact logits, first-max argmax
  int lane = tid & 63, wave = tid >> 6;
  int tok0 = (bid - 1536) * 8;
  for (int i = 0; i < 2; ++i) {
    int li = wave * 2 + i;
    int t = tok0 + li;
    const float* xp = x + (size_t)t * HD + lane * 16;
    float4 x0 = *(const float4*)xp,       x1 = *(const float4*)(xp + 4);
    float4 x2 = *(const float4*)(xp + 8), x3 = *(const float4*)(xp + 12);
    // bf16 copy of the x row while it's in registers (A operand for gemm1)
    {
      alignas(16) u16 b[16] = {
        f2bf(x0.x), f2bf(x0.y), f2bf(x0.z), f2bf(x0.w),
        f2bf(x1.x), f2bf(x1.y), f2bf(x1.z), f2bf(x1.w),
        f2bf(x2.x), f2bf(x2.y), f2bf(x2.z), f2bf(x2.w),
        f2bf(x3.x), f2bf(x3.y), f2bf(x3.z), f2bf(x3.w)};
      u16* xd = xbf + (size_t)t * HD + lane * 16;
      *(float4*)xd       = *(const float4*)&b[0];
      *(float4*)(xd + 8) = *(const float4*)&b[8];
    }
    float acc[NE];
    for (int e = 0; e < NE; ++e) {
      const float* gp = gw + e * HD + lane * 16;
      float4 g0 = *(const float4*)gp,       g1 = *(const float4*)(gp + 4);
      float4 g2 = *(const float4*)(gp + 8), g3 = *(const float4*)(gp + 12);
      acc[e] = x0.x*g0.x + x0.y*g0.y + x0.z*g0.z + x0.w*g0.w
             + x1.x*g1.x + x1.y*g1.y + x1.z*g1.z + x1.w*g1.w
             + x2.x*g2.x + x2.y*g2.y + x2.z*g2.z + x2.w*g2.w
             + x3.x*g3.x + x3.y*g3.y + x3.z*g3.z + x3.w*g3.w;
    }
    for (int off = 32; off >= 1; off >>= 1)
      for (int e = 0; e < NE; ++e) acc[e] += __shfl_xor(acc[e], off, 64);
    if (lane == 0) {
      int be = 0; float bv = acc[0];
      for (int e = 1; e < NE; ++e) if (acc[e] > bv) { bv = acc[e]; be = e; }
      sexp[li] = be;
    }
  }
  __syncthreads();
  if (tid < NE) {
    int c = 0;
    for (int i = 0; i < 8; ++i) c += (sexp[i] == tid) ? 1 : 0;
    sbase[tid] = c ? atomicAdd(&counts[tid], c) : 0;
  }
  __syncthreads();
  if (tid < 8) {
    int e = sexp[tid], rank = 0;
    for (int i = 0; i < tid; ++i) rank += (sexp[i] == e) ? 1 : 0;
    tlist[e * TOK + sbase[e] + rank] = tok0 + tid;
  }
}

// Swizzle scheme (both GEMMs): LDS tiles are linear [rows][32] bf16 (64B rows).
// Physical 16B slot s at row r holds logical slot s ^ ((r>>1)&3) (bijective);
// applied on the global SOURCE at stage time and on the ds_read address —
// both sides, same involution (all fragment row bases are multiples of 16).

// ---- gemm1: gathered xbf(bf16) @ [g 64 rows ++ u 64 rows] -> inter bf16
// grid 8192: e=bid&7 (XCD L2 locality), q=(bid>>3)&3 (64 d-cols), tile=bid>>5
// 1024 active blocks = 4/CU. gload_lds(16B) double-buffer, one barrier/K32.
__global__ __launch_bounds__(256) void gemm1_kernel(
    const u16* __restrict__ xbf, const u16* __restrict__ wgT,
    const u16* __restrict__ wuT,
    const int* __restrict__ counts, const int* __restrict__ tlist,
    u16* __restrict__ inter)
{
  int bid = blockIdx.x;
  int e = bid & 7, q = (bid >> 3) & 3, tile = bid >> 5;
  int cnt = counts[e];
  int row0 = tile * 64;
  if (row0 >= cnt) return;

  __shared__ int stok[64];
  __shared__ __align__(16) u16 xA[2][64 * 32];    // 2 x 4KB
  __shared__ __align__(16) u16 sB[2][128 * 32];   // 2 x 8KB (g 64 ++ u 64)

  int tid = threadIdx.x, lane = tid & 63, wave = tid >> 6;
  if (tid < 64) {
    int r = row0 + tid;
    stok[tid] = tlist[e * TOK + (r < cnt ? r : cnt - 1)];
  }
  __syncthreads();
  int rmax = cnt - row0; if (rmax > 64) rmax = 64;

  int col = lane & 15, quad = lane >> 4;
  int soff = ((lane & 3) ^ ((lane >> 3) & 3)) * 8;  // staging src swizzle
  int rsub = lane >> 2;                             // row within 16-row chunk
  int xsl8 = (quad ^ ((col >> 1) & 3)) * 8;         // read-side swizzle

  // per-lane staging sources
  const u16* aS = xbf + (size_t)stok[wave * 16 + rsub] * HD + soff;
  const u16* bS[2];
#pragma unroll
  for (int jj = 0; jj < 2; ++jj) {
    int r = wave * 32 + jj * 16 + rsub;             // 0..127
    bS[jj] = (r < 64)
        ? (wgT + ((size_t)e * DD + q * 64 + r) * HD + soff)
        : (wuT + ((size_t)e * DD + q * 64 + (r - 64)) * HD + soff);
  }

  floatx4 acc[4][2];
  floatx4 zz = {0.f, 0.f, 0.f, 0.f};
#pragma unroll
  for (int m = 0; m < 4; ++m)
#pragma unroll
    for (int j = 0; j < 2; ++j) acc[m][j] = zz;

  // prologue: stage K-step 0 into buffer 0
  gl16(aS, &xA[0][wave * 512]);
#pragma unroll
  for (int jj = 0; jj < 2; ++jj) gl16(bS[jj], &sB[0][(wave * 2 + jj) * 512]);
  __syncthreads();

  for (int t = 0; t < HD / 32; ++t) {
    int b = t & 1;
    if (t + 1 < HD / 32) {                          // stage next K-step
      int k1 = (t + 1) * 32;
      gl16(aS + k1, &xA[b ^ 1][wave * 512]);
#pragma unroll
      for (int jj = 0; jj < 2; ++jj) gl16(bS[jj] + k1, &sB[b ^ 1][(wave * 2 + jj) * 512]);
    }
    short8 af[4], bfr[2];
#pragma unroll
    for (int m = 0; m < 4; ++m)
      af[m] = *(const short8*)&xA[b][(m * 16 + col) * 32 + xsl8];
    bfr[0] = *(const short8*)&sB[b][(wave * 16 + col) * 32 + xsl8];
    bfr[1] = *(const short8*)&sB[b][(64 + wave * 16 + col) * 32 + xsl8];
#pragma unroll
    for (int m = 0; m < 4; ++m)
#pragma unroll
      for (int j = 0; j < 2; ++j)
        acc[m][j] = __builtin_amdgcn_mfma_f32_16x16x32_bf16(af[m], bfr[j], acc[m][j], 0, 0, 0);
    __syncthreads();   // drains gloads (vmcnt) + ds_reads (lgkm) for swap
  }

#pragma unroll
  for (int m = 0; m < 4; ++m)
#pragma unroll
    for (int r = 0; r < 4; ++r) {
      int row = m * 16 + quad * 4 + r;       // C layout: col=lane&15, row=quad*4+reg
      if (row < rmax) {
        float g = acc[m][0][r]; g = g > 0.f ? g : 0.f;
        float u = acc[m][1][r];
        inter[(size_t)stok[row] * DD + q * 64 + wave * 16 + col] = f2bf(g * g * u);
      }
    }
}

// ---- gemm2: gathered inter(bf16) @ wdT eighth (128 out-cols) -> out fp32
// grid 16384: e=bid&7, q=(bid>>3)&7, tile=bid>>6. 2048 active blocks = 8/CU.
__global__ __launch_bounds__(256) void gemm2_kernel(
    const u16* __restrict__ inter, const u16* __restrict__ wdT,
    const int* __restrict__ counts, const int* __restrict__ tlist,
    float* __restrict__ out)
{
  int bid = blockIdx.x;
  int e = bid & 7, q = (bid >> 3) & 7, tile = bid >> 6;
  int cnt = counts[e];
  int row0 = tile * 64;
  if (row0 >= cnt) return;
  int n0 = q * 128;

  __shared__ int stok[64];
  __shared__ __align__(16) u16 xA[2][64 * 32];    // 2 x 4KB
  __shared__ __align__(16) u16 sB[2][128 * 32];   // 2 x 8KB; epilogue reuse
  float (*st)[132] = (float(*)[132])&sB[0][0];    // 16*132*4 = 8448B < 16KB

  int tid = threadIdx.x, lane = tid & 63, wave = tid >> 6;
  if (tid < 64) {
    int r = row0 + tid;
    stok[tid] = tlist[e * TOK + (r < cnt ? r : cnt - 1)];
  }
  __syncthreads();
  int rmax = cnt - row0; if (rmax > 64) rmax = 64;

  int col = lane & 15, quad = lane >> 4;
  int soff = ((lane & 3) ^ ((lane >> 3) & 3)) * 8;
  int rsub = lane >> 2;
  int xsl8 = (quad ^ ((col >> 1) & 3)) * 8;

  const u16* aS = inter + (size_t)stok[wave * 16 + rsub] * DD + soff;
  const u16* bS[2];
#pragma unroll
  for (int jj = 0; jj < 2; ++jj) {
    int r = wave * 32 + jj * 16 + rsub;             // 0..127
    bS[jj] = wdT + ((size_t)e * HD + n0 + r) * DD + soff;
  }

  floatx4 acc[4][2];
  floatx4 zz = {0.f, 0.f, 0.f, 0.f};
#pragma unroll
  for (int m = 0; m < 4; ++m)
#pragma unroll
    for (int j = 0; j < 2; ++j) acc[m][j] = zz;

  gl16(aS, &xA[0][wave * 512]);
#pragma unroll
  for (int jj = 0; jj < 2; ++jj) gl16(bS[jj], &sB[0][(wave * 2 + jj) * 512]);
  __syncthreads();

  for (int t = 0; t < DD / 32; ++t) {
    int b = t & 1;
    if (t + 1 < DD / 32) {
      int k1 = (t + 1) * 32;
      gl16(aS + k1, &xA[b ^ 1][wave * 512]);
#pragma unroll
      for (int jj = 0; jj < 2; ++jj) gl16(bS[jj] + k1, &sB[b ^ 1][(wave * 2 + jj) * 512]);
    }
    short8 af[4], bfr[2];
#pragma unroll
    for (int m = 0; m < 4; ++m)
      af[m] = *(const short8*)&xA[b][(m * 16 + col) * 32 + xsl8];
#pragma unroll
    for (int j = 0; j < 2; ++j)
      bfr[j] = *(const short8*)&sB[b][(wave * 32 + j * 16 + col) * 32 + xsl8];
#pragma unroll
    for (int m = 0; m < 4; ++m)
#pragma unroll
      for (int j = 0; j < 2; ++j)
        acc[m][j] = __builtin_amdgcn_mfma_f32_16x16x32_bf16(af[m], bfr[j], acc[m][j], 0, 0, 0);
    __syncthreads();
  }

  // epilogue: 16 rows x 128 fp32 at a time through LDS -> coalesced stores
  for (int m = 0; m < 4; ++m) {
    __syncthreads();
#pragma unroll
    for (int j = 0; j < 2; ++j)
#pragma unroll
      for (int r = 0; r < 4; ++r)
        st[quad * 4 + r][wave * 32 + j * 16 + col] = acc[m][j][r];
    __syncthreads();
#pragma unroll
    for (int i = 0; i < 2; ++i) {
      int id = i * 256 + tid;
      int r = id >> 5, c4 = (id & 31) * 4;
      int row = m * 16 + r;
      if (row < rmax)
        *(float4*)(out + (size_t)stok[row] * HD + n0 + c4) = *(const float4*)&st[r][c4];
    }
  }
}

// ---------------- launch ---------------------------------------------------
extern "C" void kernel_launch(void* const* d_in, const int* in_sizes, int n_in,
                              void* d_out, int out_size, void* d_ws, size_t ws_size,
                              hipStream_t stream) {
  const float* x  = (const float*)d_in[0];
  const float* gw = (const float*)d_in[1];
  const float* wg = (const float*)d_in[2];
  const float* wu = (const float*)d_in[3];
  const float* wd = (const float*)d_in[4];
  float* out = (float*)d_out;

  char* ws = (char*)d_ws;
  int* counts = (int*)ws;                        // 256 B
  int* tlist  = (int*)(ws + 256);                // 512 KB
  u16* wgT   = (u16*)(ws + 524544);              // 4 MB
  u16* wuT   = wgT + (size_t)NE * DD * HD;       // 4 MB
  u16* wdT   = wuT + (size_t)NE * DD * HD;       // 4 MB
  u16* inter = wdT + (size_t)NE * HD * DD;       // 8 MB; total ~20.5 MiB
  // bf16 x staged in d_out: written by prep, read by gemm1, then fully
  // overwritten by gemm2's stores (stream-ordered, safe).
  u16* xbf   = (u16*)d_out;

  hipMemsetAsync(counts, 0, NE * sizeof(int), stream);
  prep_kernel<<<1536 + TOK / 8, 256, 0, stream>>>(wg, wu, wd, x, gw,
                                                  wgT, wuT, wdT, xbf, counts, tlist);
  gemm1_kernel<<<8192, 256, 0, stream>>>(xbf, wgT, wuT, counts, tlist, inter);
  gemm2_kernel<<<16384, 256, 0, stream>>>(inter, wdT, counts, tlist, out);
}

// Round 6
// 216.803 us; speedup vs baseline: 1.0675x; 1.0675x over previous
//
#include <hip/hip_runtime.h>
#include <hip/hip_bf16.h>

#define TOK 16384
#define HD  1024
#define DD  256
#define NE  8

typedef __attribute__((ext_vector_type(8))) short short8;
typedef __attribute__((ext_vector_type(4))) float floatx4;
typedef unsigned short u16;

static __device__ __forceinline__ u16 f2bf(float f) {
  __hip_bfloat16 h = __float2bfloat16(f);
  return *reinterpret_cast<u16*>(&h);
}
// convert 8 consecutive fp32 (16B-aligned) -> bf16 short8
static __device__ __forceinline__ short8 cvt8(const float* p) {
  float4 a = *(const float4*)p;
  float4 b = *(const float4*)(p + 4);
  u16 t[8] = {f2bf(a.x), f2bf(a.y), f2bf(a.z), f2bf(a.w),
              f2bf(b.x), f2bf(b.y), f2bf(b.z), f2bf(b.w)};
  return *(short8*)t;
}

// async direct global->LDS: wave writes lds_base + lane*16 (1KB/instr),
// per-lane global source (pre-swizzled upstream).
static __device__ __forceinline__ void gl16(const u16* g, u16* l) {
  __builtin_amdgcn_global_load_lds(
      (const __attribute__((address_space(1))) void*)g,
      (__attribute__((address_space(3))) void*)l, 16, 0, 0);
}

// ---- prep: weight transpose->bf16 (blocks 0..1535) + router (blocks 1536..2559)
// router: 16 tokens/block, 4 tokens per wave batched through one gw pass.
// NO cross-block atomics: emits per-chunk histogram hcnt[e][1024] and eid[]
// with plain stores; scatter_kernel builds tlist/counts afterwards.
__global__ __launch_bounds__(256) void prep_kernel(
    const float* __restrict__ wg, const float* __restrict__ wu,
    const float* __restrict__ wd, const float* __restrict__ x,
    const float* __restrict__ gw,
    u16* __restrict__ wgT, u16* __restrict__ wuT, u16* __restrict__ wdT,
    u16* __restrict__ xbf,
    int* __restrict__ hcnt, int* __restrict__ eid)
{
  __shared__ u16 tile[64][72];
  __shared__ int sexp[16];
  int bid = blockIdx.x;
  int tid = threadIdx.x;

  if (bid < 1536) {
    const float* src; u16* dst; int R, C;
    if (bid < 512)       { src = wg; dst = wgT; R = HD; C = DD; }
    else if (bid < 1024) { src = wu; dst = wuT; R = HD; C = DD; bid -= 512; }
    else                 { src = wd; dst = wdT; R = DD; C = HD; bid -= 1024; }
    int e = bid >> 6, t = bid & 63;
    int ntc = C >> 6;
    int tr = t / ntc, tc = t % ntc;
    int r = tid >> 2, c0 = (tid & 3) * 16;
    const float* s = src + (size_t)e * R * C + (size_t)(tr * 64 + r) * C + tc * 64 + c0;
    *(short8*)&tile[r][c0]     = cvt8(s);
    *(short8*)&tile[r][c0 + 8] = cvt8(s + 8);
    __syncthreads();
    int c = tid >> 2, r0 = (tid & 3) * 16;
    alignas(16) u16 buf[16];
    for (int j = 0; j < 16; ++j) buf[j] = tile[r0 + j][c];
    u16* d = dst + (size_t)e * R * C + (size_t)(tc * 64 + c) * R + tr * 64 + r0;
    *(float4*)(d)     = *(const float4*)&buf[0];
    *(float4*)(d + 8) = *(const float4*)&buf[8];
    return;
  }

  // ---- router: 4 tokens per wave, batched through one gw pass
  int lane = tid & 63, wave = tid >> 6;
  int rb = bid - 1536;                       // router chunk 0..1023
  int tok0 = rb * 16 + wave * 4;
  float4 xr[4][4];
#pragma unroll
  for (int t = 0; t < 4; ++t) {
    const float* xp = x + (size_t)(tok0 + t) * HD + lane * 16;
    xr[t][0] = *(const float4*)xp;
    xr[t][1] = *(const float4*)(xp + 4);
    xr[t][2] = *(const float4*)(xp + 8);
    xr[t][3] = *(const float4*)(xp + 12);
  }
#pragma unroll
  for (int t = 0; t < 4; ++t) {
    alignas(16) u16 b[16] = {
      f2bf(xr[t][0].x), f2bf(xr[t][0].y), f2bf(xr[t][0].z), f2bf(xr[t][0].w),
      f2bf(xr[t][1].x), f2bf(xr[t][1].y), f2bf(xr[t][1].z), f2bf(xr[t][1].w),
      f2bf(xr[t][2].x), f2bf(xr[t][2].y), f2bf(xr[t][2].z), f2bf(xr[t][2].w),
      f2bf(xr[t][3].x), f2bf(xr[t][3].y), f2bf(xr[t][3].z), f2bf(xr[t][3].w)};
    u16* xd = xbf + (size_t)(tok0 + t) * HD + lane * 16;
    *(float4*)xd       = *(const float4*)&b[0];
    *(float4*)(xd + 8) = *(const float4*)&b[8];
  }
  float acc[4][NE];
#pragma unroll
  for (int e = 0; e < NE; ++e) {
    const float* gp = gw + e * HD + lane * 16;
    float4 g0 = *(const float4*)gp,       g1 = *(const float4*)(gp + 4);
    float4 g2 = *(const float4*)(gp + 8), g3 = *(const float4*)(gp + 12);
#pragma unroll
    for (int t = 0; t < 4; ++t) {
      acc[t][e] = xr[t][0].x*g0.x + xr[t][0].y*g0.y + xr[t][0].z*g0.z + xr[t][0].w*g0.w
                + xr[t][1].x*g1.x + xr[t][1].y*g1.y + xr[t][1].z*g1.z + xr[t][1].w*g1.w
                + xr[t][2].x*g2.x + xr[t][2].y*g2.y + xr[t][2].z*g2.z + xr[t][2].w*g2.w
                + xr[t][3].x*g3.x + xr[t][3].y*g3.y + xr[t][3].z*g3.z + xr[t][3].w*g3.w;
    }
  }
  for (int off = 32; off >= 1; off >>= 1)
#pragma unroll
    for (int t = 0; t < 4; ++t)
#pragma unroll
      for (int e = 0; e < NE; ++e) acc[t][e] += __shfl_xor(acc[t][e], off, 64);
  if (lane == 0) {
#pragma unroll
    for (int t = 0; t < 4; ++t) {
      int be = 0; float bv = acc[t][0];
      for (int e = 1; e < NE; ++e) if (acc[t][e] > bv) { bv = acc[t][e]; be = e; }
      sexp[wave * 4 + t] = be;
    }
  }
  __syncthreads();
  if (tid < NE) {
    int c = 0;
    for (int i = 0; i < 16; ++i) c += (sexp[i] == tid) ? 1 : 0;
    hcnt[tid * 1024 + rb] = c;               // plain store, no atomics
  }
  if (tid < 16) eid[rb * 16 + tid] = sexp[tid];
}

// ---- scatter: build tlist + counts from hcnt/eid (no atomics anywhere).
// grid 256: block b owns tokens [64b, 64b+64) = router chunks 4b..4b+3.
__global__ __launch_bounds__(256) void scatter_kernel(
    const int* __restrict__ eid, const int* __restrict__ hcnt,
    int* __restrict__ counts, int* __restrict__ tlist)
{
  __shared__ int seid[64];
  __shared__ int sp[NE][33];
  __shared__ int sbase0[NE];
  int bid = blockIdx.x, tid = threadIdx.x;
  int t0 = bid * 64;
  if (tid < 64) seid[tid] = eid[t0 + tid];
  // prefix over chunks < 4*bid, strided-parallel: 8 experts x 32 lanes
  int e = tid >> 5, i = tid & 31;
  int lim = 4 * bid;
  int s = 0;
  for (int c = i; c < lim; c += 32) s += hcnt[e * 1024 + c];
  sp[e][i] = s;
  __syncthreads();
  if (tid < NE) {
    int b = 0;
    for (int j = 0; j < 32; ++j) b += sp[tid][j];
    sbase0[tid] = b;
  }
  if (bid == 0) {   // block 0 also writes total counts (replaces memset+atomics)
    int st = 0;
    for (int c = i; c < 1024; c += 32) st += hcnt[e * 1024 + c];
    __syncthreads();            // sbase0 reads of sp done
    sp[e][i] = st;
    __syncthreads();
    if (tid < NE) {
      int b = 0;
      for (int j = 0; j < 32; ++j) b += sp[tid][j];
      counts[tid] = b;
    }
  }
  __syncthreads();
  if (tid < 64) {
    int ee = seid[tid], rank = 0;
    for (int j = 0; j < tid; ++j) rank += (seid[j] == ee) ? 1 : 0;
    tlist[ee * TOK + sbase0[ee] + rank] = t0 + tid;
  }
}

// Swizzle scheme (both GEMMs): LDS tiles are linear [rows][32] bf16 (64B rows).
// Physical 16B slot s at row r holds logical slot s ^ ((r>>1)&3) (bijective);
// applied on the global SOURCE at stage time and on the ds_read address —
// both sides, same involution (all fragment row bases are multiples of 16).

// ---- gemm1: gathered xbf(bf16) @ [g 64 rows ++ u 64 rows] -> inter bf16
// grid 8192: e=bid&7 (XCD L2 locality), q=(bid>>3)&3 (64 d-cols), tile=bid>>5
// 1024 active blocks = 4/CU. gload_lds(16B) double-buffer, one barrier/K32.
__global__ __launch_bounds__(256) void gemm1_kernel(
    const u16* __restrict__ xbf, const u16* __restrict__ wgT,
    const u16* __restrict__ wuT,
    const int* __restrict__ counts, const int* __restrict__ tlist,
    u16* __restrict__ inter)
{
  int bid = blockIdx.x;
  int e = bid & 7, q = (bid >> 3) & 3, tile = bid >> 5;
  int cnt = counts[e];
  int row0 = tile * 64;
  if (row0 >= cnt) return;

  __shared__ int stok[64];
  __shared__ __align__(16) u16 xA[2][64 * 32];    // 2 x 4KB
  __shared__ __align__(16) u16 sB[2][128 * 32];   // 2 x 8KB (g 64 ++ u 64)

  int tid = threadIdx.x, lane = tid & 63, wave = tid >> 6;
  if (tid < 64) {
    int r = row0 + tid;
    stok[tid] = tlist[e * TOK + (r < cnt ? r : cnt - 1)];
  }
  __syncthreads();
  int rmax = cnt - row0; if (rmax > 64) rmax = 64;

  int col = lane & 15, quad = lane >> 4;
  int soff = ((lane & 3) ^ ((lane >> 3) & 3)) * 8;  // staging src swizzle
  int rsub = lane >> 2;                             // row within 16-row chunk
  int xsl8 = (quad ^ ((col >> 1) & 3)) * 8;         // read-side swizzle

  // per-lane staging sources
  const u16* aS = xbf + (size_t)stok[wave * 16 + rsub] * HD + soff;
  const u16* bS[2];
#pragma unroll
  for (int jj = 0; jj < 2; ++jj) {
    int r = wave * 32 + jj * 16 + rsub;             // 0..127
    bS[jj] = (r < 64)
        ? (wgT + ((size_t)e * DD + q * 64 + r) * HD + soff)
        : (wuT + ((size_t)e * DD + q * 64 + (r - 64)) * HD + soff);
  }

  floatx4 acc[4][2];
  floatx4 zz = {0.f, 0.f, 0.f, 0.f};
#pragma unroll
  for (int m = 0; m < 4; ++m)
#pragma unroll
    for (int j = 0; j < 2; ++j) acc[m][j] = zz;

  // prologue: stage K-step 0 into buffer 0
  gl16(aS, &xA[0][wave * 512]);
#pragma unroll
  for (int jj = 0; jj < 2; ++jj) gl16(bS[jj], &sB[0][(wave * 2 + jj) * 512]);
  __syncthreads();

  for (int t = 0; t < HD / 32; ++t) {
    int b = t & 1;
    if (t + 1 < HD / 32) {                          // stage next K-step
      int k1 = (t + 1) * 32;
      gl16(aS + k1, &xA[b ^ 1][wave * 512]);
#pragma unroll
      for (int jj = 0; jj < 2; ++jj) gl16(bS[jj] + k1, &sB[b ^ 1][(wave * 2 + jj) * 512]);
    }
    short8 af[4], bfr[2];
#pragma unroll
    for (int m = 0; m < 4; ++m)
      af[m] = *(const short8*)&xA[b][(m * 16 + col) * 32 + xsl8];
    bfr[0] = *(const short8*)&sB[b][(wave * 16 + col) * 32 + xsl8];
    bfr[1] = *(const short8*)&sB[b][(64 + wave * 16 + col) * 32 + xsl8];
#pragma unroll
    for (int m = 0; m < 4; ++m)
#pragma unroll
      for (int j = 0; j < 2; ++j)
        acc[m][j] = __builtin_amdgcn_mfma_f32_16x16x32_bf16(af[m], bfr[j], acc[m][j], 0, 0, 0);
    __syncthreads();   // drains gloads (vmcnt) + ds_reads (lgkm) for swap
  }

#pragma unroll
  for (int m = 0; m < 4; ++m)
#pragma unroll
    for (int r = 0; r < 4; ++r) {
      int row = m * 16 + quad * 4 + r;       // C layout: col=lane&15, row=quad*4+reg
      if (row < rmax) {
        float g = acc[m][0][r]; g = g > 0.f ? g : 0.f;
        float u = acc[m][1][r];
        inter[(size_t)stok[row] * DD + q * 64 + wave * 16 + col] = f2bf(g * g * u);
      }
    }
}

// ---- gemm2: gathered inter(bf16) @ wdT eighth (128 out-cols) -> out fp32
// grid 16384: e=bid&7, q=(bid>>3)&7, tile=bid>>6. 2048 active blocks = 8/CU.
__global__ __launch_bounds__(256) void gemm2_kernel(
    const u16* __restrict__ inter, const u16* __restrict__ wdT,
    const int* __restrict__ counts, const int* __restrict__ tlist,
    float* __restrict__ out)
{
  int bid = blockIdx.x;
  int e = bid & 7, q = (bid >> 3) & 7, tile = bid >> 6;
  int cnt = counts[e];
  int row0 = tile * 64;
  if (row0 >= cnt) return;
  int n0 = q * 128;

  __shared__ int stok[64];
  __shared__ __align__(16) u16 xA[2][64 * 32];    // 2 x 4KB
  __shared__ __align__(16) u16 sB[2][128 * 32];   // 2 x 8KB; epilogue reuse
  float (*st)[132] = (float(*)[132])&sB[0][0];    // 16*132*4 = 8448B < 16KB

  int tid = threadIdx.x, lane = tid & 63, wave = tid >> 6;
  if (tid < 64) {
    int r = row0 + tid;
    stok[tid] = tlist[e * TOK + (r < cnt ? r : cnt - 1)];
  }
  __syncthreads();
  int rmax = cnt - row0; if (rmax > 64) rmax = 64;

  int col = lane & 15, quad = lane >> 4;
  int soff = ((lane & 3) ^ ((lane >> 3) & 3)) * 8;
  int rsub = lane >> 2;
  int xsl8 = (quad ^ ((col >> 1) & 3)) * 8;

  const u16* aS = inter + (size_t)stok[wave * 16 + rsub] * DD + soff;
  const u16* bS[2];
#pragma unroll
  for (int jj = 0; jj < 2; ++jj) {
    int r = wave * 32 + jj * 16 + rsub;             // 0..127
    bS[jj] = wdT + ((size_t)e * HD + n0 + r) * DD + soff;
  }

  floatx4 acc[4][2];
  floatx4 zz = {0.f, 0.f, 0.f, 0.f};
#pragma unroll
  for (int m = 0; m < 4; ++m)
#pragma unroll
    for (int j = 0; j < 2; ++j) acc[m][j] = zz;

  gl16(aS, &xA[0][wave * 512]);
#pragma unroll
  for (int jj = 0; jj < 2; ++jj) gl16(bS[jj], &sB[0][(wave * 2 + jj) * 512]);
  __syncthreads();

  for (int t = 0; t < DD / 32; ++t) {
    int b = t & 1;
    if (t + 1 < DD / 32) {
      int k1 = (t + 1) * 32;
      gl16(aS + k1, &xA[b ^ 1][wave * 512]);
#pragma unroll
      for (int jj = 0; jj < 2; ++jj) gl16(bS[jj] + k1, &sB[b ^ 1][(wave * 2 + jj) * 512]);
    }
    short8 af[4], bfr[2];
#pragma unroll
    for (int m = 0; m < 4; ++m)
      af[m] = *(const short8*)&xA[b][(m * 16 + col) * 32 + xsl8];
#pragma unroll
    for (int j = 0; j < 2; ++j)
      bfr[j] = *(const short8*)&sB[b][(wave * 32 + j * 16 + col) * 32 + xsl8];
#pragma unroll
    for (int m = 0; m < 4; ++m)
#pragma unroll
      for (int j = 0; j < 2; ++j)
        acc[m][j] = __builtin_amdgcn_mfma_f32_16x16x32_bf16(af[m], bfr[j], acc[m][j], 0, 0, 0);
    __syncthreads();
  }

  // epilogue: 16 rows x 128 fp32 at a time through LDS -> coalesced stores
  for (int m = 0; m < 4; ++m) {
    __syncthreads();
#pragma unroll
    for (int j = 0; j < 2; ++j)
#pragma unroll
      for (int r = 0; r < 4; ++r)
        st[quad * 4 + r][wave * 32 + j * 16 + col] = acc[m][j][r];
    __syncthreads();
#pragma unroll
    for (int i = 0; i < 2; ++i) {
      int id = i * 256 + tid;
      int r = id >> 5, c4 = (id & 31) * 4;
      int row = m * 16 + r;
      if (row < rmax)
        *(float4*)(out + (size_t)stok[row] * HD + n0 + c4) = *(const float4*)&st[r][c4];
    }
  }
}

// ---------------- launch ---------------------------------------------------
extern "C" void kernel_launch(void* const* d_in, const int* in_sizes, int n_in,
                              void* d_out, int out_size, void* d_ws, size_t ws_size,
                              hipStream_t stream) {
  const float* x  = (const float*)d_in[0];
  const float* gw = (const float*)d_in[1];
  const float* wg = (const float*)d_in[2];
  const float* wu = (const float*)d_in[3];
  const float* wd = (const float*)d_in[4];
  float* out = (float*)d_out;

  char* ws = (char*)d_ws;
  int* counts = (int*)ws;                        // 256 B
  int* tlist  = (int*)(ws + 256);                // 512 KB
  u16* wgT   = (u16*)(ws + 524544);              // 4 MB
  u16* wuT   = wgT + (size_t)NE * DD * HD;       // 4 MB
  u16* wdT   = wuT + (size_t)NE * DD * HD;       // 4 MB
  u16* inter = wdT + (size_t)NE * HD * DD;       // 8 MB
  int* eid   = (int*)(inter + (size_t)TOK * DD); // 64 KB
  int* hcnt  = eid + TOK;                        // 32 KB; total ~20.6 MiB
  // bf16 x staged in d_out: written by prep, read by gemm1, then fully
  // overwritten by gemm2's stores (stream-ordered, safe).
  u16* xbf   = (u16*)d_out;

  prep_kernel<<<2560, 256, 0, stream>>>(wg, wu, wd, x, gw,
                                        wgT, wuT, wdT, xbf, hcnt, eid);
  scatter_kernel<<<256, 256, 0, stream>>>(eid, hcnt, counts, tlist);
  gemm1_kernel<<<8192, 256, 0, stream>>>(xbf, wgT, wuT, counts, tlist, inter);
  gemm2_kernel<<<16384, 256, 0, stream>>>(inter, wdT, counts, tlist, out);
}

// Round 8
// 212.834 us; speedup vs baseline: 1.0874x; 1.0186x over previous
//
#include <hip/hip_runtime.h>
#include <hip/hip_bf16.h>

#define TOK 16384
#define HD  1024
#define DD  256
#define NE  8

typedef __attribute__((ext_vector_type(8))) short short8;
typedef __attribute__((ext_vector_type(4))) float floatx4;
typedef unsigned short u16;

static __device__ __forceinline__ u16 f2bf(float f) {
  __hip_bfloat16 h = __float2bfloat16(f);
  return *reinterpret_cast<u16*>(&h);
}
// convert 8 consecutive fp32 (16B-aligned) -> bf16 short8
static __device__ __forceinline__ short8 cvt8(const float* p) {
  float4 a = *(const float4*)p;
  float4 b = *(const float4*)(p + 4);
  u16 t[8] = {f2bf(a.x), f2bf(a.y), f2bf(a.z), f2bf(a.w),
              f2bf(b.x), f2bf(b.y), f2bf(b.z), f2bf(b.w)};
  return *(short8*)t;
}

// async direct global->LDS: wave writes lds_base + lane*16 (1KB/instr),
// per-lane global source (pre-swizzled upstream).
static __device__ __forceinline__ void gl16(const u16* g, u16* l) {
  __builtin_amdgcn_global_load_lds(
      (const __attribute__((address_space(1))) void*)g,
      (__attribute__((address_space(3))) void*)l, 16, 0, 0);
}

// ---- prep: weight transpose->bf16 (blocks 0..1535) + router (blocks 1536..2559)
// (verified round-6 version, unchanged)
__global__ __launch_bounds__(256) void prep_kernel(
    const float* __restrict__ wg, const float* __restrict__ wu,
    const float* __restrict__ wd, const float* __restrict__ x,
    const float* __restrict__ gw,
    u16* __restrict__ wgT, u16* __restrict__ wuT, u16* __restrict__ wdT,
    u16* __restrict__ xbf,
    int* __restrict__ hcnt, int* __restrict__ eid)
{
  __shared__ u16 tile[64][72];
  __shared__ int sexp[16];
  int bid = blockIdx.x;
  int tid = threadIdx.x;

  if (bid < 1536) {
    const float* src; u16* dst; int R, C;
    if (bid < 512)       { src = wg; dst = wgT; R = HD; C = DD; }
    else if (bid < 1024) { src = wu; dst = wuT; R = HD; C = DD; bid -= 512; }
    else                 { src = wd; dst = wdT; R = DD; C = HD; bid -= 1024; }
    int e = bid >> 6, t = bid & 63;
    int ntc = C >> 6;
    int tr = t / ntc, tc = t % ntc;
    int r = tid >> 2, c0 = (tid & 3) * 16;
    const float* s = src + (size_t)e * R * C + (size_t)(tr * 64 + r) * C + tc * 64 + c0;
    *(short8*)&tile[r][c0]     = cvt8(s);
    *(short8*)&tile[r][c0 + 8] = cvt8(s + 8);
    __syncthreads();
    int c = tid >> 2, r0 = (tid & 3) * 16;
    alignas(16) u16 buf[16];
    for (int j = 0; j < 16; ++j) buf[j] = tile[r0 + j][c];
    u16* d = dst + (size_t)e * R * C + (size_t)(tc * 64 + c) * R + tr * 64 + r0;
    *(float4*)(d)     = *(const float4*)&buf[0];
    *(float4*)(d + 8) = *(const float4*)&buf[8];
    return;
  }

  // ---- router: 4 tokens per wave, batched through one gw pass
  int lane = tid & 63, wave = tid >> 6;
  int rb = bid - 1536;                       // router chunk 0..1023
  int tok0 = rb * 16 + wave * 4;
  float4 xr[4][4];
#pragma unroll
  for (int t = 0; t < 4; ++t) {
    const float* xp = x + (size_t)(tok0 + t) * HD + lane * 16;
    xr[t][0] = *(const float4*)xp;
    xr[t][1] = *(const float4*)(xp + 4);
    xr[t][2] = *(const float4*)(xp + 8);
    xr[t][3] = *(const float4*)(xp + 12);
  }
#pragma unroll
  for (int t = 0; t < 4; ++t) {
    alignas(16) u16 b[16] = {
      f2bf(xr[t][0].x), f2bf(xr[t][0].y), f2bf(xr[t][0].z), f2bf(xr[t][0].w),
      f2bf(xr[t][1].x), f2bf(xr[t][1].y), f2bf(xr[t][1].z), f2bf(xr[t][1].w),
      f2bf(xr[t][2].x), f2bf(xr[t][2].y), f2bf(xr[t][2].z), f2bf(xr[t][2].w),
      f2bf(xr[t][3].x), f2bf(xr[t][3].y), f2bf(xr[t][3].z), f2bf(xr[t][3].w)};
    u16* xd = xbf + (size_t)(tok0 + t) * HD + lane * 16;
    *(float4*)xd       = *(const float4*)&b[0];
    *(float4*)(xd + 8) = *(const float4*)&b[8];
  }
  float acc[4][NE];
#pragma unroll
  for (int e = 0; e < NE; ++e) {
    const float* gp = gw + e * HD + lane * 16;
    float4 g0 = *(const float4*)gp,       g1 = *(const float4*)(gp + 4);
    float4 g2 = *(const float4*)(gp + 8), g3 = *(const float4*)(gp + 12);
#pragma unroll
    for (int t = 0; t < 4; ++t) {
      acc[t][e] = xr[t][0].x*g0.x + xr[t][0].y*g0.y + xr[t][0].z*g0.z + xr[t][0].w*g0.w
                + xr[t][1].x*g1.x + xr[t][1].y*g1.y + xr[t][1].z*g1.z + xr[t][1].w*g1.w
                + xr[t][2].x*g2.x + xr[t][2].y*g2.y + xr[t][2].z*g2.z + xr[t][2].w*g2.w
                + xr[t][3].x*g3.x + xr[t][3].y*g3.y + xr[t][3].z*g3.z + xr[t][3].w*g3.w;
    }
  }
  for (int off = 32; off >= 1; off >>= 1)
#pragma unroll
    for (int t = 0; t < 4; ++t)
#pragma unroll
      for (int e = 0; e < NE; ++e) acc[t][e] += __shfl_xor(acc[t][e], off, 64);
  if (lane == 0) {
#pragma unroll
    for (int t = 0; t < 4; ++t) {
      int be = 0; float bv = acc[t][0];
      for (int e = 1; e < NE; ++e) if (acc[t][e] > bv) { bv = acc[t][e]; be = e; }
      sexp[wave * 4 + t] = be;
    }
  }
  __syncthreads();
  if (tid < NE) {
    int c = 0;
    for (int i = 0; i < 16; ++i) c += (sexp[i] == tid) ? 1 : 0;
    hcnt[tid * 1024 + rb] = c;               // plain store, no atomics
  }
  if (tid < 16) eid[rb * 16 + tid] = sexp[tid];
}

// ---- scatter: build tlist + counts from hcnt/eid (verified round-6 version).
__global__ __launch_bounds__(256) void scatter_kernel(
    const int* __restrict__ eid, const int* __restrict__ hcnt,
    int* __restrict__ counts, int* __restrict__ tlist)
{
  __shared__ int seid[64];
  __shared__ int sp[NE][33];
  __shared__ int sbase0[NE];
  int bid = blockIdx.x, tid = threadIdx.x;
  int t0 = bid * 64;
  if (tid < 64) seid[tid] = eid[t0 + tid];
  int e = tid >> 5, i = tid & 31;
  int lim = 4 * bid;
  int s = 0;
  for (int c = i; c < lim; c += 32) s += hcnt[e * 1024 + c];
  sp[e][i] = s;
  __syncthreads();
  if (tid < NE) {
    int b = 0;
    for (int j = 0; j < 32; ++j) b += sp[tid][j];
    sbase0[tid] = b;
  }
  if (bid == 0) {   // block 0 also writes total counts
    int st = 0;
    for (int c = i; c < 1024; c += 32) st += hcnt[e * 1024 + c];
    __syncthreads();
    sp[e][i] = st;
    __syncthreads();
    if (tid < NE) {
      int b = 0;
      for (int j = 0; j < 32; ++j) b += sp[tid][j];
      counts[tid] = b;
    }
  }
  __syncthreads();
  if (tid < 64) {
    int ee = seid[tid], rank = 0;
    for (int j = 0; j < tid; ++j) rank += (seid[j] == ee) ? 1 : 0;
    tlist[ee * TOK + sbase0[ee] + rank] = t0 + tid;
  }
}

// Swizzle: LDS tiles linear [rows][32] bf16; physical 16B slot s at row r
// holds logical slot s ^ ((r>>1)&3); applied on global SOURCE + ds_read addr.
//
// K-loop sync (T4 counted-vmcnt, FENCED): raw s_barrier is NOT a memory
// fence in LLVM — every barrier is bracketed by sched_barrier(0) and every
// waitcnt asm carries a "memory" clobber, pinning {stage | barrier |
// ds_read+MFMA | barrier} into their phases (m201 discipline, rule #18).

// ---- gemm1: gathered xbf(bf16) @ [g 64 rows ++ u 64 rows] -> inter bf16
// grid 8192: e=bid&7 (XCD L2 locality), q=(bid>>3)&3 (64 d-cols), tile=bid>>5
__global__ __launch_bounds__(256) void gemm1_kernel(
    const u16* __restrict__ xbf, const u16* __restrict__ wgT,
    const u16* __restrict__ wuT,
    const int* __restrict__ counts, const int* __restrict__ tlist,
    u16* __restrict__ inter)
{
  int bid = blockIdx.x;
  int e = bid & 7, q = (bid >> 3) & 3, tile = bid >> 5;
  int cnt = counts[e];
  int row0 = tile * 64;
  if (row0 >= cnt) return;

  __shared__ int stok[64];
  __shared__ __align__(16) u16 xA[2][64 * 32];    // 2 x 4KB
  __shared__ __align__(16) u16 sB[2][128 * 32];   // 2 x 8KB (g 64 ++ u 64)

  int tid = threadIdx.x, lane = tid & 63, wave = tid >> 6;
  if (tid < 64) {
    int r = row0 + tid;
    stok[tid] = tlist[e * TOK + (r < cnt ? r : cnt - 1)];
  }
  __syncthreads();
  int rmax = cnt - row0; if (rmax > 64) rmax = 64;

  int col = lane & 15, quad = lane >> 4;
  int soff = ((lane & 3) ^ ((lane >> 3) & 3)) * 8;  // staging src swizzle
  int rsub = lane >> 2;                             // row within 16-row chunk
  int xsl8 = (quad ^ ((col >> 1) & 3)) * 8;         // read-side swizzle

  const u16* aS = xbf + (size_t)stok[wave * 16 + rsub] * HD + soff;
  const u16* bS[2];
#pragma unroll
  for (int jj = 0; jj < 2; ++jj) {
    int r = wave * 32 + jj * 16 + rsub;             // 0..127
    bS[jj] = (r < 64)
        ? (wgT + ((size_t)e * DD + q * 64 + r) * HD + soff)
        : (wuT + ((size_t)e * DD + q * 64 + (r - 64)) * HD + soff);
  }

  floatx4 acc[4][2];
  floatx4 zz = {0.f, 0.f, 0.f, 0.f};
#pragma unroll
  for (int m = 0; m < 4; ++m)
#pragma unroll
    for (int j = 0; j < 2; ++j) acc[m][j] = zz;

  // prologue: stage K-step 0 into buffer 0 (3 loads/wave, stay in flight)
  gl16(aS, &xA[0][wave * 512]);
#pragma unroll
  for (int jj = 0; jj < 2; ++jj) gl16(bS[jj], &sB[0][(wave * 2 + jj) * 512]);

  for (int t = 0; t < HD / 32; ++t) {
    int b = t & 1;
    if (t + 1 < HD / 32) {                          // stage next K-step
      int k1 = (t + 1) * 32;
      gl16(aS + k1, &xA[b ^ 1][wave * 512]);
#pragma unroll
      for (int jj = 0; jj < 2; ++jj) gl16(bS[jj] + k1, &sB[b ^ 1][(wave * 2 + jj) * 512]);
      asm volatile("s_waitcnt vmcnt(3)" ::: "memory");   // step t's 3 retired
    } else {
      asm volatile("s_waitcnt vmcnt(0)" ::: "memory");
    }
    __builtin_amdgcn_sched_barrier(0);
    __builtin_amdgcn_s_barrier();                   // all waves' step t staged
    __builtin_amdgcn_sched_barrier(0);
    short8 af[4], bfr[2];
#pragma unroll
    for (int m = 0; m < 4; ++m)
      af[m] = *(const short8*)&xA[b][(m * 16 + col) * 32 + xsl8];
    bfr[0] = *(const short8*)&sB[b][(wave * 16 + col) * 32 + xsl8];
    bfr[1] = *(const short8*)&sB[b][(64 + wave * 16 + col) * 32 + xsl8];
#pragma unroll
    for (int m = 0; m < 4; ++m)
#pragma unroll
      for (int j = 0; j < 2; ++j)
        acc[m][j] = __builtin_amdgcn_mfma_f32_16x16x32_bf16(af[m], bfr[j], acc[m][j], 0, 0, 0);
    __builtin_amdgcn_sched_barrier(0);
    __builtin_amdgcn_s_barrier();                   // reads done before buf reuse
    __builtin_amdgcn_sched_barrier(0);
  }

#pragma unroll
  for (int m = 0; m < 4; ++m)
#pragma unroll
    for (int r = 0; r < 4; ++r) {
      int row = m * 16 + quad * 4 + r;       // C layout: col=lane&15, row=quad*4+reg
      if (row < rmax) {
        float g = acc[m][0][r]; g = g > 0.f ? g : 0.f;
        float u = acc[m][1][r];
        inter[(size_t)stok[row] * DD + q * 64 + wave * 16 + col] = f2bf(g * g * u);
      }
    }
}

// ---- gemm2: gathered inter(bf16) @ wdT eighth (128 out-cols) -> out fp32
// grid 16384: e=bid&7, q=(bid>>3)&7, tile=bid>>6. Same fenced counted-vmcnt.
__global__ __launch_bounds__(256) void gemm2_kernel(
    const u16* __restrict__ inter, const u16* __restrict__ wdT,
    const int* __restrict__ counts, const int* __restrict__ tlist,
    float* __restrict__ out)
{
  int bid = blockIdx.x;
  int e = bid & 7, q = (bid >> 3) & 7, tile = bid >> 6;
  int cnt = counts[e];
  int row0 = tile * 64;
  if (row0 >= cnt) return;
  int n0 = q * 128;

  __shared__ int stok[64];
  __shared__ __align__(16) u16 xA[2][64 * 32];    // 2 x 4KB
  __shared__ __align__(16) u16 sB[2][128 * 32];   // 2 x 8KB; epilogue reuse
  float (*st)[132] = (float(*)[132])&sB[0][0];    // 16*132*4 = 8448B < 16KB

  int tid = threadIdx.x, lane = tid & 63, wave = tid >> 6;
  if (tid < 64) {
    int r = row0 + tid;
    stok[tid] = tlist[e * TOK + (r < cnt ? r : cnt - 1)];
  }
  __syncthreads();
  int rmax = cnt - row0; if (rmax > 64) rmax = 64;

  int col = lane & 15, quad = lane >> 4;
  int soff = ((lane & 3) ^ ((lane >> 3) & 3)) * 8;
  int rsub = lane >> 2;
  int xsl8 = (quad ^ ((col >> 1) & 3)) * 8;

  const u16* aS = inter + (size_t)stok[wave * 16 + rsub] * DD + soff;
  const u16* bS[2];
#pragma unroll
  for (int jj = 0; jj < 2; ++jj) {
    int r = wave * 32 + jj * 16 + rsub;             // 0..127
    bS[jj] = wdT + ((size_t)e * HD + n0 + r) * DD + soff;
  }

  floatx4 acc[4][2];
  floatx4 zz = {0.f, 0.f, 0.f, 0.f};
#pragma unroll
  for (int m = 0; m < 4; ++m)
#pragma unroll
    for (int j = 0; j < 2; ++j) acc[m][j] = zz;

  gl16(aS, &xA[0][wave * 512]);
#pragma unroll
  for (int jj = 0; jj < 2; ++jj) gl16(bS[jj], &sB[0][(wave * 2 + jj) * 512]);

  for (int t = 0; t < DD / 32; ++t) {
    int b = t & 1;
    if (t + 1 < DD / 32) {
      int k1 = (t + 1) * 32;
      gl16(aS + k1, &xA[b ^ 1][wave * 512]);
#pragma unroll
      for (int jj = 0; jj < 2; ++jj) gl16(bS[jj] + k1, &sB[b ^ 1][(wave * 2 + jj) * 512]);
      asm volatile("s_waitcnt vmcnt(3)" ::: "memory");
    } else {
      asm volatile("s_waitcnt vmcnt(0)" ::: "memory");
    }
    __builtin_amdgcn_sched_barrier(0);
    __builtin_amdgcn_s_barrier();
    __builtin_amdgcn_sched_barrier(0);
    short8 af[4], bfr[2];
#pragma unroll
    for (int m = 0; m < 4; ++m)
      af[m] = *(const short8*)&xA[b][(m * 16 + col) * 32 + xsl8];
#pragma unroll
    for (int j = 0; j < 2; ++j)
      bfr[j] = *(const short8*)&sB[b][(wave * 32 + j * 16 + col) * 32 + xsl8];
#pragma unroll
    for (int m = 0; m < 4; ++m)
#pragma unroll
      for (int j = 0; j < 2; ++j)
        acc[m][j] = __builtin_amdgcn_mfma_f32_16x16x32_bf16(af[m], bfr[j], acc[m][j], 0, 0, 0);
    __builtin_amdgcn_sched_barrier(0);
    __builtin_amdgcn_s_barrier();
    __builtin_amdgcn_sched_barrier(0);
  }

  // epilogue: 16 rows x 128 fp32 at a time through LDS -> coalesced stores
  for (int m = 0; m < 4; ++m) {
    __syncthreads();
#pragma unroll
    for (int j = 0; j < 2; ++j)
#pragma unroll
      for (int r = 0; r < 4; ++r)
        st[quad * 4 + r][wave * 32 + j * 16 + col] = acc[m][j][r];
    __syncthreads();
#pragma unroll
    for (int i = 0; i < 2; ++i) {
      int id = i * 256 + tid;
      int r = id >> 5, c4 = (id & 31) * 4;
      int row = m * 16 + r;
      if (row < rmax)
        *(float4*)(out + (size_t)stok[row] * HD + n0 + c4) = *(const float4*)&st[r][c4];
    }
  }
}

// ---------------- launch ---------------------------------------------------
extern "C" void kernel_launch(void* const* d_in, const int* in_sizes, int n_in,
                              void* d_out, int out_size, void* d_ws, size_t ws_size,
                              hipStream_t stream) {
  const float* x  = (const float*)d_in[0];
  const float* gw = (const float*)d_in[1];
  const float* wg = (const float*)d_in[2];
  const float* wu = (const float*)d_in[3];
  const float* wd = (const float*)d_in[4];
  float* out = (float*)d_out;

  char* ws = (char*)d_ws;
  int* counts = (int*)ws;                        // 256 B
  int* tlist  = (int*)(ws + 256);                // 512 KB
  u16* wgT   = (u16*)(ws + 524544);              // 4 MB
  u16* wuT   = wgT + (size_t)NE * DD * HD;       // 4 MB
  u16* wdT   = wuT + (size_t)NE * DD * HD;       // 4 MB
  u16* inter = wdT + (size_t)NE * HD * DD;       // 8 MB
  int* eid   = (int*)(inter + (size_t)TOK * DD); // 64 KB
  int* hcnt  = eid + TOK;                        // 32 KB; total ~20.6 MiB
  // bf16 x staged in d_out: written by prep, read by gemm1, then fully
  // overwritten by gemm2's stores (stream-ordered, safe).
  u16* xbf   = (u16*)d_out;

  prep_kernel<<<2560, 256, 0, stream>>>(wg, wu, wd, x, gw,
                                        wgT, wuT, wdT, xbf, hcnt, eid);
  scatter_kernel<<<256, 256, 0, stream>>>(eid, hcnt, counts, tlist);
  gemm1_kernel<<<8192, 256, 0, stream>>>(xbf, wgT, wuT, counts, tlist, inter);
  gemm2_kernel<<<16384, 256, 0, stream>>>(inter, wdT, counts, tlist, out);
}